// Round 3
// baseline (644.021 us; speedup 1.0000x reference)
//
#include <hip/hip_runtime.h>

// Problem constants (match reference)
#define D     4
#define MUL   16
#define S0    8
#define S1    8
#define SOUT  8
#define NP3   8
#define NP4   4

#define EPB   16          // edges per group (4 per wave)
#define TPB   256
#define GRID  1024        // 4 blocks/CU persistent
// Wt row stride per edge: 192 entries + 8 pad = 200 floats (16B-aligned,
// 200%32==8 -> per-edge broadcast b128 reads hit distinct banks)
#define WSTRIDE 200

// Wave-scope LDS ordering only: every Wt row's producers and consumers are the
// same wave (edge eL's 16 lanes live in wave eL>>2); DS ops from one wave
// execute in order, so no s_barrier (and no vmcnt(0) drain) is needed.
__device__ __forceinline__ void wave_lds_fence() {
    __builtin_amdgcn_fence(__ATOMIC_RELEASE, "wavefront");
    __builtin_amdgcn_wave_barrier();
    __builtin_amdgcn_fence(__ATOMIC_ACQUIRE, "wavefront");
}

__device__ __forceinline__ float4 sel8(const float4 (&a)[8], int s) {
    switch (s & 7) {          // s is SGPR-resident -> uniform branch tree
        case 0: return a[0];
        case 1: return a[1];
        case 2: return a[2];
        case 3: return a[3];
        case 4: return a[4];
        case 5: return a[5];
        case 6: return a[6];
        default: return a[7];
    }
}

#define ADDC(idx) acc[idx].x += cv.x; acc[idx].y += cv.y; acc[idx].z += cv.z; acc[idx].w += cv.w; break;
__device__ __forceinline__ void addsel8(float4 (&acc)[8], int s, float4 cv) {
    switch (s & 7) {
        case 0: ADDC(0)
        case 1: ADDC(1)
        case 2: ADDC(2)
        case 3: ADDC(3)
        case 4: ADDC(4)
        case 5: ADDC(5)
        case 6: ADDC(6)
        default: ADDC(7)
    }
}

__global__ __launch_bounds__(TPB, 4)   // cap 128 VGPRs: keep a_cur+a_next+acc live
void tp_fused_kernel(const float* __restrict__ x0,
                     const int*   __restrict__ i0,
                     const float* __restrict__ x1,
                     const float* __restrict__ C3,
                     const float* __restrict__ C4,
                     const int*   __restrict__ p3,
                     const int*   __restrict__ p4,
                     float*       __restrict__ out,
                     int E)
{
    __shared__ float Wt[EPB * WSTRIDE];

    const int tid = threadIdx.x;
    const int eL  = tid >> 4;
    const int u   = tid & 15;
    const int ngroups = (E + EPB - 1) / EPB;
    const int G = gridDim.x;
    const long Emax = (long)E - 1;

    // ---- uniform path metadata (scalar loads) ----
    int q3s0[NP3], q3so[NP3];
    #pragma unroll
    for (int p = 0; p < NP3; ++p) { q3s0[p] = p3[p * 3 + 0]; q3so[p] = p3[p * 3 + 2]; }
    int q4s0[NP4], q4so[NP4];
    #pragma unroll
    for (int p = 0; p < NP4; ++p) { q4s0[p] = p4[p * 4 + 0]; q4so[p] = p4[p * 4 + 3]; }

    // ---- per-lane W-build assignment: lane u owns W3 cells (p=u>>1, i=(u&1)*2+ii)
    //      and W4 cell (p=u>>2, i=u&3); output index vectorized as float4 ----
    const int p3w = u >> 1;
    const int i3a = (u & 1) * 2;
    const int p4w = u >> 2;
    const int i4w = u & 3;
    const int s1w3 = p3[p3w * 3 + 1];
    const int s1w4 = p4[p4w * 4 + 1];
    const int s2w4 = p4[p4w * 4 + 2];
    const float4* c3r = (const float4*)(C3 + p3w * 64);              // [i*4 + j] over k
    const float4* c4r = (const float4*)(C4 + p4w * 256 + i4w * 64);  // [j*4 + k] over m

    float* wr = &Wt[eL * WSTRIDE];

    int g = blockIdx.x;
    if (g >= ngroups) return;

    // ---- prologue: group g's gather in flight before first compute ----
    int row_cur;
    {
        const long ec0 = min((long)g * EPB + eL, Emax);
        row_cur = i0[ec0];
    }
    float4 a_cur[S0];
    {
        const float4* ar = (const float4*)(x0 + (long)row_cur * (S0 * MUL * D));
        #pragma unroll
        for (int s = 0; s < S0; ++s) a_cur[s] = ar[s * MUL + u];
    }
    int gn = g + G;
    int row_next = 0;
    if (gn < ngroups) row_next = i0[min((long)gn * EPB + eL, Emax)];

    while (true) {
        const long e  = (long)g * EPB + eL;
        const long ec = min(e, Emax);

        // ---- W build for current group (these loads issue BEFORE the next
        //      gathers, so vmcnt waits on them don't drain the gather queue) ----
        const float* x1r = x1 + ec * (S1 * D);
        const float4 b3 = *(const float4*)(x1r + s1w3 * D);
        const float4 b4 = *(const float4*)(x1r + s1w4 * D);
        const float4 cc = *(const float4*)(x1r + s2w4 * D);

        #pragma unroll
        for (int ii = 0; ii < 2; ++ii) {
            const int i = i3a + ii;
            const float4 r0 = c3r[i * 4 + 0];
            const float4 r1 = c3r[i * 4 + 1];
            const float4 r2 = c3r[i * 4 + 2];
            const float4 r3 = c3r[i * 4 + 3];
            float4 w;
            w.x = b3.x * r0.x + b3.y * r1.x + b3.z * r2.x + b3.w * r3.x;
            w.y = b3.x * r0.y + b3.y * r1.y + b3.z * r2.y + b3.w * r3.y;
            w.z = b3.x * r0.z + b3.y * r1.z + b3.z * r2.z + b3.w * r3.z;
            w.w = b3.x * r0.w + b3.y * r1.w + b3.z * r2.w + b3.w * r3.w;
            *(float4*)(wr + p3w * 16 + i * 4) = w;
        }
        {
            float wx = 0.f, wy = 0.f, wz = 0.f, ww = 0.f;
            const float bj[4] = { b4.x, b4.y, b4.z, b4.w };
            const float ck[4] = { cc.x, cc.y, cc.z, cc.w };
            #pragma unroll
            for (int j = 0; j < 4; ++j) {
                #pragma unroll
                for (int k = 0; k < 4; ++k) {
                    const float f = bj[j] * ck[k];
                    const float4 r = c4r[j * 4 + k];
                    wx += f * r.x; wy += f * r.y; wz += f * r.z; ww += f * r.w;
                }
            }
            const float4 wv = make_float4(wx, wy, wz, ww);
            *(float4*)(wr + 128 + p4w * 16 + i4w * 4) = wv;
        }

        // ---- issue next group's gathers (consumed next iteration) ----
        const bool have_next = (gn < ngroups);
        float4 a_next[S0];
        if (have_next) {
            const float4* arn = (const float4*)(x0 + (long)row_next * (S0 * MUL * D));
            #pragma unroll
            for (int s = 0; s < S0; ++s) a_next[s] = arn[s * MUL + u];
        }
        // ---- prefetch i0 two groups ahead ----
        int row_next2 = 0;
        const int gn2 = gn + G;
        if (have_next && gn2 < ngroups)
            row_next2 = i0[min((long)gn2 * EPB + eL, Emax)];

        wave_lds_fence();   // W writes visible to this wave's readers

        // ---- contributions from a_cur (loaded an iteration ago: latency hidden) ----
        float4 acc[SOUT];
        #pragma unroll
        for (int s = 0; s < SOUT; ++s) acc[s] = make_float4(0.f, 0.f, 0.f, 0.f);

        #pragma unroll
        for (int p = 0; p < NP3 + NP4; ++p) {
            const int s0s = (p < NP3) ? q3s0[p] : q4s0[p - NP3];
            const int os  = (p < NP3) ? q3so[p] : q4so[p - NP3];
            const float4 av = sel8(a_cur, s0s);
            const float4 w0 = *(const float4*)(wr + p * 16 + 0);
            const float4 w1 = *(const float4*)(wr + p * 16 + 4);
            const float4 w2 = *(const float4*)(wr + p * 16 + 8);
            const float4 w3v = *(const float4*)(wr + p * 16 + 12);
            float4 cv;
            cv.x = av.x * w0.x + av.y * w1.x + av.z * w2.x + av.w * w3v.x;
            cv.y = av.x * w0.y + av.y * w1.y + av.z * w2.y + av.w * w3v.y;
            cv.z = av.x * w0.z + av.y * w1.z + av.z * w2.z + av.w * w3v.z;
            cv.w = av.x * w0.w + av.y * w1.w + av.z * w2.w + av.w * w3v.w;
            addsel8(acc, os, cv);
        }

        wave_lds_fence();   // Wt reads complete before next iteration's writes

        // ---- plain coalesced stores (L2 write-coalescing; NT regressed WRITE_SIZE) ----
        if (e < (long)E) {
            float* o = out + e * (SOUT * MUL * D);
            #pragma unroll
            for (int s = 0; s < SOUT; ++s)
                *(float4*)(o + (s * MUL + u) * 4) = acc[s];
        }

        if (!have_next) break;
        g = gn; gn = gn2; row_next = row_next2;
        #pragma unroll
        for (int s = 0; s < S0; ++s) a_cur[s] = a_next[s];
    }
}

extern "C" void kernel_launch(void* const* d_in, const int* in_sizes, int n_in,
                              void* d_out, int out_size, void* d_ws, size_t ws_size,
                              hipStream_t stream) {
    const float* x0 = (const float*)d_in[0];
    const int*   i0 = (const int*)  d_in[1];
    const float* x1 = (const float*)d_in[2];
    const float* C3 = (const float*)d_in[3];
    const float* C4 = (const float*)d_in[4];
    const int*   p3 = (const int*)  d_in[5];
    const int*   p4 = (const int*)  d_in[6];
    float* out = (float*)d_out;

    const int E = in_sizes[1];                 // i0 has E elements
    const int ngroups = (E + EPB - 1) / EPB;
    const int blocks = ngroups < GRID ? ngroups : GRID;
    tp_fused_kernel<<<blocks, TPB, 0, stream>>>(x0, i0, x1, C3, C4, p3, p4, out, E);
}